// Round 18
// baseline (2719.598 us; speedup 1.0000x reference)
//
#include <hip/hip_runtime.h>
#include <cstdint>

#define Hn 36
#define G4 144          // 4*H gate rows
#define TT 512
#define BB 2048

__device__ __forceinline__ float sigf(float x) { return 1.0f / (1.0f + __expf(-x)); }
__device__ __forceinline__ float tanh_fast(float x) {
    float e = __expf(2.0f * x);          // exact +-1 limits via over/underflow
    return 1.0f - 2.0f / (e + 1.0f);
}

// ---- K1 named-register weight quads (r15 l0rev, consistently ~420us) ----
#define REP9(M, P)  M(P,0) M(P,1) M(P,2) M(P,3) M(P,4) M(P,5) M(P,6) M(P,7) M(P,8)
#define DECLQ(P, i) float P##i##x, P##i##y, P##i##z, P##i##w;
#define LOADQ(P, i) { float4 _t = wp[i]; P##i##x = _t.x; P##i##y = _t.y; P##i##z = _t.z; P##i##w = _t.w; }
#define PINQ(P, i)  asm volatile("" : "+v"(P##i##x), "+v"(P##i##y), "+v"(P##i##z), "+v"(P##i##w));
#define FMAQ(P, i)                                                        \
    {  float4 hv = *(const float4*)&hb[(i) * 4];                          \
       z0 = fmaf(P##i##x, hv.x, z0); z1 = fmaf(P##i##y, hv.y, z1);        \
       z2 = fmaf(P##i##z, hv.z, z2); z3 = fmaf(P##i##w, hv.w, z3); }

// array-based dots (fallback kernel only)
#define DOT36(W, H, Z0, Z1, Z2, Z3)                        \
    do {                                                   \
        _Pragma("unroll") for (int _k = 0; _k < 9; ++_k) { \
            float4 hv = *(const float4*)&(H)[_k * 4];      \
            Z0 = fmaf((W)[_k * 4 + 0], hv.x, Z0);          \
            Z1 = fmaf((W)[_k * 4 + 1], hv.y, Z1);          \
            Z2 = fmaf((W)[_k * 4 + 2], hv.z, Z2);          \
            Z3 = fmaf((W)[_k * 4 + 3], hv.w, Z3);          \
        }                                                  \
    } while (0)

#define DOT72(W, H, Z0, Z1, Z2, Z3)                         \
    do {                                                    \
        _Pragma("unroll") for (int _k = 0; _k < 18; ++_k) { \
            float4 hv = *(const float4*)&(H)[_k * 4];       \
            Z0 = fmaf((W)[_k * 4 + 0], hv.x, Z0);           \
            Z1 = fmaf((W)[_k * 4 + 1], hv.y, Z1);           \
            Z2 = fmaf((W)[_k * 4 + 2], hv.z, Z2);           \
            Z3 = fmaf((W)[_k * 4 + 3], hv.w, Z3);           \
        }                                                   \
    } while (0)

// ============ K1: layer-0 REVERSE scan, full batch -> h0r (151 MB ws) ========
#define SG1 4
#define NTK1 (SG1 * G4)   // 576
__global__ __launch_bounds__(NTK1) void l0rev_kernel(
    const float* __restrict__ x,
    const float* __restrict__ Wih, const float* __restrict__ Whh,
    const float* __restrict__ bih, const float* __restrict__ bhh,
    float* __restrict__ h0r)
{
    const int tid = threadIdx.x;
    const int cc  = tid / G4;
    const int g   = tid % G4;
    const int b   = blockIdx.x * SG1 + cc;

    __shared__ float xs[SG1][TT];
    __shared__ float hs[SG1][40];
    __shared__ float zs[SG1][G4];

    for (int i = g; i < TT; i += G4) xs[cc][i] = x[(size_t)b * TT + i];

    REP9(DECLQ, R)
    {
        const float4* wp = (const float4*)(Whh + g * Hn);
        REP9(LOADQ, R)
    }
    float wx   = Wih[g];
    float bias = bih[g] + bhh[g];
    REP9(PINQ, R)
    asm volatile("" : "+v"(wx), "+v"(bias));

    if (g < 40) hs[cc][g] = 0.0f;
    float c = 0.0f;
    __syncthreads();

    float* dst = h0r + (size_t)b * TT * Hn;

    for (int s = 0; s < TT; ++s) {
        const int t = TT - 1 - s;
        float z0 = fmaf(xs[cc][t], wx, bias), z1 = 0.f, z2 = 0.f, z3 = 0.f;
        {
            const float* hb = hs[cc];
            REP9(FMAQ, R)
        }
        zs[cc][g] = (z0 + z1) + (z2 + z3);
        __syncthreads();
        if (g < Hn) {
            float zi = zs[cc][g], zf = zs[cc][g + 36], zg = zs[cc][g + 72], zo = zs[cc][g + 108];
            c = sigf(zf) * c + sigf(zi) * tanh_fast(zg);
            float h = sigf(zo) * tanh_fast(c);
            hs[cc][g] = h;
            dst[(size_t)t * Hn + g] = h;
        }
        __syncthreads();
    }
}

// ==== K2: gate-local combine + K-split shfl, 1 barrier/step, 8 chains/block ==
// Thread (u, ch, part): partial dots for gate rows {u,u+36,u+72,u+108} of L0
// and L1 over half the K-dim; shfl_xor(8) completes z in-register; part0
// combines L0 (c0), part1 combines L1 (c1) + stages h0r. Double-buffered h.
#define SG2 8
#define NT2 576          // 9 waves, all active
#define NB2 (BB / SG2)   // 256 blocks
#define HST 44           // h-buffer chain stride (44%32=12 -> conflict-free)

__global__ __launch_bounds__(NT2) void fused_fl_kernel(
    const float* __restrict__ x,
    const float* __restrict__ Wih0f, const float* __restrict__ Whh0f,
    const float* __restrict__ bih0f, const float* __restrict__ bhh0f,
    const float* __restrict__ Wih1f, const float* __restrict__ Whh1f,
    const float* __restrict__ bih1f, const float* __restrict__ bhh1f,
    const float* __restrict__ Wih1r,
    const float* __restrict__ bih1r, const float* __restrict__ bhh1r,
    const float* __restrict__ fcW, const float* __restrict__ fcb,
    const float* __restrict__ h0r,
    float* __restrict__ out)
{
    const int tid  = threadIdx.x;
    const int u    = tid >> 4;        // 0..35
    const int part = (tid >> 3) & 1;  // K-half
    const int ch   = tid & 7;         // chain
    const int base = blockIdx.x * SG2;

    __shared__ float4 wt0t[10 * G4];   // Whh0f transposed, quad 9 zero-padded
    __shared__ float4 wt1t[18 * G4];   // Wih1f transposed
    __shared__ float4 wt3t[10 * G4];   // Whh1f transposed, quad 9 zero-padded
    __shared__ float xs[SG2][TT + 2];
    __shared__ float h0fb[2][SG2][HST];
    __shared__ float h0rb[2][SG2][HST];
    __shared__ float h1b[2][SG2][HST];
    __shared__ float ztail[SG2][G4];
    __shared__ float red[SG2][Hn];

    // ---------------- one-time staging ----------------
    for (int i = tid; i < 10 * G4; i += NT2) {
        int q = i / G4, r = i % G4;
        float4 z4; z4.x = 0.f; z4.y = 0.f; z4.z = 0.f; z4.w = 0.f;
        wt0t[i] = (q < 9) ? ((const float4*)(Whh0f + r * Hn))[q] : z4;
        wt3t[i] = (q < 9) ? ((const float4*)(Whh1f + r * Hn))[q] : z4;
    }
    for (int i = tid; i < 18 * G4; i += NT2) {
        int q = i / G4, r = i % G4;
        wt1t[i] = ((const float4*)(Wih1f + r * 72))[q];
    }
    for (int i = tid; i < SG2 * (TT + 2); i += NT2) {
        int c = i / (TT + 2), t = i % (TT + 2);
        xs[c][t] = (t < TT) ? x[(size_t)(base + c) * TT + t] : 0.0f;
    }
    for (int i = tid; i < 2 * SG2 * HST; i += NT2) {
        (&h0fb[0][0][0])[i] = 0.0f;
        (&h0rb[0][0][0])[i] = 0.0f;
        (&h1b[0][0][0])[i]  = 0.0f;
    }

    const int r0 = u, r1 = u + 36, r2 = u + 72, r3 = u + 108;
    // per-role constants (8 scalars, no arrays)
    float wxi = 0.f, wxf = 0.f, wxg = 0.f, wxo = 0.f;
    float bi, bf_, bg_, bo;
    if (part == 0) {
        wxi = Wih0f[r0]; wxf = Wih0f[r1]; wxg = Wih0f[r2]; wxo = Wih0f[r3];
        bi  = bih0f[r0] + bhh0f[r0]; bf_ = bih0f[r1] + bhh0f[r1];
        bg_ = bih0f[r2] + bhh0f[r2]; bo  = bih0f[r3] + bhh0f[r3];
    } else {
        bi  = bih1f[r0] + bhh1f[r0]; bf_ = bih1f[r1] + bhh1f[r1];
        bg_ = bih1f[r2] + bhh1f[r2]; bo  = bih1f[r3] + bhh1f[r3];
    }

    // precomputed weight bases for this thread's K-half
    const float4* w0b = wt0t + (part * 5) * G4;   // L0: quads part*5 .. +4
    const float4* w1b = wt1t + (part * 9) * G4;   // L1-ih: quads part*9 .. +8
    const float4* w3b = wt3t + (part * 5) * G4;   // L1-hh: quads part*5 .. +4
    const int hq0 = part * 5 * 4;                 // L0 h offset (floats)

    const float* srow = h0r + (size_t)(base + ch) * TT * Hn + u;  // part1 stream
    float c0 = 0.f, c1 = 0.f, rvv = 0.f;
    __syncthreads();

    // ---- prologue: h0f(0) from x(0), h=0 (forget term vanishes); stage h0r(0)
    if (part == 0) {
        float x0 = xs[ch][0];
        float zi = fmaf(x0, wxi, bi), zg = fmaf(x0, wxg, bg_), zo = fmaf(x0, wxo, bo);
        c0 = sigf(zi) * tanh_fast(zg);
        h0fb[0][ch][u] = sigf(zo) * tanh_fast(c0);
    } else {
        h0rb[0][ch][u] = srow[0];
        rvv = srow[Hn];                            // h0r(1)
    }
    __syncthreads();

    int cur = 0;
    for (int t = 0; t < TT; ++t) {
        float rv2 = (part == 1 && t + 2 < TT) ? srow[(size_t)(t + 2) * Hn] : 0.0f;

        const float* h0c = &h0fb[cur][ch][0];
        const float* hrc = &h0rb[cur][ch][0];
        const float* h1c = &h1b[cur][ch][0];
        const float* hsrc = part ? hrc : h0c;      // L1-ih operand half

        float zA = 0.f, zB = 0.f, zC = 0.f, zD = 0.f;   // L0 partials
        float yA = 0.f, yB = 0.f, yC = 0.f, yD = 0.f;   // L1 partials

#pragma unroll
        for (int i = 0; i < 5; ++i) {              // L0 (pad quad is zero-weighted)
            float4 w_0 = w0b[i * G4 + r0], w_1 = w0b[i * G4 + r1];
            float4 w_2 = w0b[i * G4 + r2], w_3 = w0b[i * G4 + r3];
            float4 h = *(const float4*)&h0c[hq0 + i * 4];
            zA = fmaf(w_0.x, h.x, zA); zA = fmaf(w_0.y, h.y, zA);
            zA = fmaf(w_0.z, h.z, zA); zA = fmaf(w_0.w, h.w, zA);
            zB = fmaf(w_1.x, h.x, zB); zB = fmaf(w_1.y, h.y, zB);
            zB = fmaf(w_1.z, h.z, zB); zB = fmaf(w_1.w, h.w, zB);
            zC = fmaf(w_2.x, h.x, zC); zC = fmaf(w_2.y, h.y, zC);
            zC = fmaf(w_2.z, h.z, zC); zC = fmaf(w_2.w, h.w, zC);
            zD = fmaf(w_3.x, h.x, zD); zD = fmaf(w_3.y, h.y, zD);
            zD = fmaf(w_3.z, h.z, zD); zD = fmaf(w_3.w, h.w, zD);
        }
#pragma unroll
        for (int i = 0; i < 9; ++i) {              // L1-ih (h0f or h0r half)
            float4 w_0 = w1b[i * G4 + r0], w_1 = w1b[i * G4 + r1];
            float4 w_2 = w1b[i * G4 + r2], w_3 = w1b[i * G4 + r3];
            float4 h = *(const float4*)&hsrc[i * 4];
            yA = fmaf(w_0.x, h.x, yA); yA = fmaf(w_0.y, h.y, yA);
            yA = fmaf(w_0.z, h.z, yA); yA = fmaf(w_0.w, h.w, yA);
            yB = fmaf(w_1.x, h.x, yB); yB = fmaf(w_1.y, h.y, yB);
            yB = fmaf(w_1.z, h.z, yB); yB = fmaf(w_1.w, h.w, yB);
            yC = fmaf(w_2.x, h.x, yC); yC = fmaf(w_2.y, h.y, yC);
            yC = fmaf(w_2.z, h.z, yC); yC = fmaf(w_2.w, h.w, yC);
            yD = fmaf(w_3.x, h.x, yD); yD = fmaf(w_3.y, h.y, yD);
            yD = fmaf(w_3.z, h.z, yD); yD = fmaf(w_3.w, h.w, yD);
        }
#pragma unroll
        for (int i = 0; i < 5; ++i) {              // L1-hh (pad quad zero-weighted)
            float4 w_0 = w3b[i * G4 + r0], w_1 = w3b[i * G4 + r1];
            float4 w_2 = w3b[i * G4 + r2], w_3 = w3b[i * G4 + r3];
            float4 h = *(const float4*)&h1c[hq0 + i * 4];
            yA = fmaf(w_0.x, h.x, yA); yA = fmaf(w_0.y, h.y, yA);
            yA = fmaf(w_0.z, h.z, yA); yA = fmaf(w_0.w, h.w, yA);
            yB = fmaf(w_1.x, h.x, yB); yB = fmaf(w_1.y, h.y, yB);
            yB = fmaf(w_1.z, h.z, yB); yB = fmaf(w_1.w, h.w, yB);
            yC = fmaf(w_2.x, h.x, yC); yC = fmaf(w_2.y, h.y, yC);
            yC = fmaf(w_2.z, h.z, yC); yC = fmaf(w_2.w, h.w, yC);
            yD = fmaf(w_3.x, h.x, yD); yD = fmaf(w_3.y, h.y, yD);
            yD = fmaf(w_3.z, h.z, yD); yD = fmaf(w_3.w, h.w, yD);
        }

        // complete dots across K-halves (partner lane = tid ^ 8)
        zA += __shfl_xor(zA, 8); zB += __shfl_xor(zB, 8);
        zC += __shfl_xor(zC, 8); zD += __shfl_xor(zD, 8);
        yA += __shfl_xor(yA, 8); yB += __shfl_xor(yB, 8);
        yC += __shfl_xor(yC, 8); yD += __shfl_xor(yD, 8);

        if (part == 0) {                           // L0 combine -> h0f(t+1)
            if (t + 1 < TT) {
                float xn = xs[ch][t + 1];
                float zi = fmaf(xn, wxi, bi)  + zA;
                float zf = fmaf(xn, wxf, bf_) + zB;
                float zg = fmaf(xn, wxg, bg_) + zC;
                float zo = fmaf(xn, wxo, bo)  + zD;
                c0 = sigf(zf) * c0 + sigf(zi) * tanh_fast(zg);
                h0fb[cur ^ 1][ch][u] = sigf(zo) * tanh_fast(c0);
            }
        } else {                                   // L1 combine -> h1(t); stage h0r
            float zi = yA + bi, zf = yB + bf_, zg = yC + bg_, zo = yD + bo;
            c1 = sigf(zf) * c1 + sigf(zi) * tanh_fast(zg);
            h1b[cur ^ 1][ch][u] = sigf(zo) * tanh_fast(c1);
            if (t + 1 < TT) h0rb[cur ^ 1][ch][u] = rvv;
            rvv = rv2;
        }
        __syncthreads();
        cur ^= 1;
    }
    // final buffers: h0f(511) in h0fb[1], h0r(511) in h0rb[1], h1(511) in h1b[0]

    // ---- tail: L1 reverse single step at t=TT-1 (h0=c0=0) + FC ----
    {
        const int gpT = tid / G4, gT = tid % G4;
#pragma unroll
        for (int s2 = 0; s2 < 2; ++s2) {
            const int cc = gpT * 2 + s2;
            float zR = bih1r[gT] + bhh1r[gT];
            const float* wrq = Wih1r + gT * 72;
#pragma unroll
            for (int k = 0; k < Hn; ++k) zR = fmaf(wrq[k],      h0fb[1][cc][k], zR);
#pragma unroll
            for (int k = 0; k < Hn; ++k) zR = fmaf(wrq[36 + k], h0rb[1][cc][k], zR);
            ztail[cc][gT] = zR;
        }
    }
    __syncthreads();
    if (tid < 288) {
        const int c2 = tid / 36, i2 = tid % 36;
        float zi = ztail[c2][i2], zg = ztail[c2][i2 + 72], zo = ztail[c2][i2 + 108];
        float cR = sigf(zi) * tanh_fast(zg);   // c0=0: forget term vanishes
        float hR = sigf(zo) * tanh_fast(cR);
        red[c2][i2] = fcW[36 + i2] * hR + fcW[i2] * h1b[0][c2][i2];
    }
    __syncthreads();
    if (tid < SG2) {
        float s2 = fcb[0];
        for (int j = 0; j < Hn; ++j) s2 += red[tid][j];
        out[base + tid] = s2;
    }
}

// ================= FALLBACK PATH (zero workspace, ckpt/recompute) ============
__global__ __launch_bounds__(G4, 1) void fused_all_kernel(
    const float* __restrict__ x,
    const float* __restrict__ Wih0f, const float* __restrict__ Whh0f,
    const float* __restrict__ bih0f, const float* __restrict__ bhh0f,
    const float* __restrict__ Wih0r, const float* __restrict__ Whh0r,
    const float* __restrict__ bih0r, const float* __restrict__ bhh0r,
    const float* __restrict__ Wih1f, const float* __restrict__ Whh1f,
    const float* __restrict__ bih1f, const float* __restrict__ bhh1f,
    const float* __restrict__ Wih1r,
    const float* __restrict__ bih1r, const float* __restrict__ bhh1r,
    const float* __restrict__ fcW, const float* __restrict__ fcb,
    float* __restrict__ out)
{
    const int g = threadIdx.x;
    const int b = blockIdx.x;

    __shared__ float xs[TT];
    __shared__ float cbuf[64][Hn];
    __shared__ float ckpt_h[8][Hn], ckpt_c[8][Hn];
    __shared__ float hr[40], h0s[80], hs1[40], zs[G4], red[40];

    for (int i = g; i < TT; i += G4) xs[i] = x[(size_t)b * TT + i];

    float wr[Hn], wf[Hn];
#pragma unroll
    for (int k = 0; k < Hn; ++k) wr[k] = Whh0r[g * Hn + k];
#pragma unroll
    for (int k = 0; k < Hn; ++k) wf[k] = Whh0f[g * Hn + k];
    const float wxr = Wih0r[g], br = bih0r[g] + bhh0r[g];
    const float wxf = Wih0f[g], bf = bih0f[g] + bhh0f[g];
    float w1i[72];
#pragma unroll
    for (int k = 0; k < 72; ++k) w1i[k] = Wih1f[g * 72 + k];
    float w1h[Hn];
#pragma unroll
    for (int k = 0; k < Hn; ++k) w1h[k] = Whh1f[g * Hn + k];
    const float b1 = bih1f[g] + bhh1f[g];

    if (g < Hn) hr[g] = 0.0f;
    float cr = 0.0f;
    __syncthreads();
    for (int s = 0; s < TT; ++s) {
        const int t = TT - 1 - s;
        if ((t & 63) == 63 && g < Hn) { ckpt_h[t >> 6][g] = hr[g]; ckpt_c[t >> 6][g] = cr; }
        float z0 = fmaf(xs[t], wxr, br), z1 = 0.f, z2 = 0.f, z3 = 0.f;
        DOT36(wr, hr, z0, z1, z2, z3);
        zs[g] = (z0 + z1) + (z2 + z3);
        __syncthreads();
        if (g < Hn) {
            float zi = zs[g], zf = zs[g + 36], zg = zs[g + 72], zo = zs[g + 108];
            cr = sigf(zf) * cr + sigf(zi) * tanh_fast(zg);
            hr[g] = sigf(zo) * tanh_fast(cr);
        }
        __syncthreads();
    }

    if (g < Hn) { h0s[g] = 0.0f; hs1[g] = 0.0f; }
    float c0 = 0.0f, c1 = 0.0f;
    __syncthreads();

    for (int m = 0; m < 8; ++m) {
        if (g < Hn) { hr[g] = ckpt_h[m][g]; cr = ckpt_c[m][g]; }
        __syncthreads();
        for (int j = 0; j < 64; ++j) {
            const int t = m * 64 + 63 - j;
            float z0 = fmaf(xs[t], wxr, br), z1 = 0.f, z2 = 0.f, z3 = 0.f;
            DOT36(wr, hr, z0, z1, z2, z3);
            zs[g] = (z0 + z1) + (z2 + z3);
            __syncthreads();
            if (g < Hn) {
                float zi = zs[g], zf = zs[g + 36], zg = zs[g + 72], zo = zs[g + 108];
                cr = sigf(zf) * cr + sigf(zi) * tanh_fast(zg);
                float h = sigf(zo) * tanh_fast(cr);
                hr[g] = h;
                cbuf[t & 63][g] = h;
            }
            __syncthreads();
        }
        for (int j = 0; j < 64; ++j) {
            const int t = m * 64 + j;
            float z0 = fmaf(xs[t], wxf, bf), z1 = 0.f, z2 = 0.f, z3 = 0.f;
            DOT36(wf, h0s, z0, z1, z2, z3);
            zs[g] = (z0 + z1) + (z2 + z3);
            __syncthreads();
            if (g < Hn) {
                float zi = zs[g], zf = zs[g + 36], zg = zs[g + 72], zo = zs[g + 108];
                c0 = sigf(zf) * c0 + sigf(zi) * tanh_fast(zg);
                h0s[g] = sigf(zo) * tanh_fast(c0);
            } else if (g < 72) {
                h0s[g] = cbuf[j][g - 36];
            }
            __syncthreads();
            float y0 = b1, y1 = 0.f, y2 = 0.f, y3 = 0.f;
            DOT72(w1i, h0s, y0, y1, y2, y3);
            DOT36(w1h, hs1, y0, y1, y2, y3);
            zs[g] = (y0 + y1) + (y2 + y3);
            __syncthreads();
            if (g < Hn) {
                float zi = zs[g], zf = zs[g + 36], zg = zs[g + 72], zo = zs[g + 108];
                c1 = sigf(zf) * c1 + sigf(zi) * tanh_fast(zg);
                hs1[g] = sigf(zo) * tanh_fast(c1);
            }
            __syncthreads();
        }
    }

    float zR = bih1r[g] + bhh1r[g];
#pragma unroll
    for (int k = 0; k < 72; ++k) zR = fmaf(Wih1r[g * 72 + k], h0s[k], zR);
    zs[g] = zR;
    __syncthreads();
    if (g < Hn) {
        float zi = zs[g], zg = zs[g + 72], zo = zs[g + 108];
        float c  = sigf(zi) * tanh_fast(zg);
        float hrv = sigf(zo) * tanh_fast(c);
        red[g] = fcW[36 + g] * hrv + fcW[g] * hs1[g];
    }
    __syncthreads();
    if (g == 0) {
        float s = fcb[0];
        for (int j = 0; j < Hn; ++j) s += red[j];
        out[b] = s;
    }
}

extern "C" void kernel_launch(void* const* d_in, const int* in_sizes, int n_in,
                              void* d_out, int out_size, void* d_ws, size_t ws_size,
                              hipStream_t stream)
{
    const float* x     = (const float*)d_in[0];
    const float* Wih0f = (const float*)d_in[1];
    const float* Whh0f = (const float*)d_in[2];
    const float* bih0f = (const float*)d_in[3];
    const float* bhh0f = (const float*)d_in[4];
    const float* Wih0r = (const float*)d_in[5];
    const float* Whh0r = (const float*)d_in[6];
    const float* bih0r = (const float*)d_in[7];
    const float* bhh0r = (const float*)d_in[8];
    const float* Wih1f = (const float*)d_in[9];
    const float* Whh1f = (const float*)d_in[10];
    const float* bih1f = (const float*)d_in[11];
    const float* bhh1f = (const float*)d_in[12];
    const float* Wih1r = (const float*)d_in[13];
    const float* bih1r = (const float*)d_in[15];
    const float* bhh1r = (const float*)d_in[16];
    const float* fcW   = (const float*)d_in[17];
    const float* fcb   = (const float*)d_in[18];

    const size_t need = (size_t)BB * TT * Hn * sizeof(float);   // 151 MB (known-safe)
    if (d_ws != nullptr && ws_size >= need) {
        float* h0r = (float*)d_ws;
        l0rev_kernel<<<BB / SG1, NTK1, 0, stream>>>(x, Wih0r, Whh0r, bih0r, bhh0r, h0r);
        fused_fl_kernel<<<NB2, NT2, 0, stream>>>(
            x, Wih0f, Whh0f, bih0f, bhh0f, Wih1f, Whh1f, bih1f, bhh1f,
            Wih1r, bih1r, bhh1r, fcW, fcb, h0r, (float*)d_out);
    } else {
        fused_all_kernel<<<BB, G4, 0, stream>>>(
            x, Wih0f, Whh0f, bih0f, bhh0f, Wih0r, Whh0r, bih0r, bhh0r,
            Wih1f, Whh1f, bih1f, bhh1f, Wih1r, bih1r, bhh1r, fcW, fcb,
            (float*)d_out);
    }
}

// Round 19
// 1840.743 us; speedup vs baseline: 1.4774x; 1.4774x over previous
//
#include <hip/hip_runtime.h>
#include <cstdint>

#define Hn 36
#define G4 144          // 4*H gate rows
#define TT 512
#define BB 2048

__device__ __forceinline__ float sigf(float x) { return 1.0f / (1.0f + __expf(-x)); }
__device__ __forceinline__ float tanh_fast(float x) {
    float e = __expf(2.0f * x);          // exact +-1 limits via over/underflow
    return 1.0f - 2.0f / (e + 1.0f);
}

// ---- K1 named-register weight quads (r15 l0rev, consistently ~420us) ----
#define REP9(M, P)  M(P,0) M(P,1) M(P,2) M(P,3) M(P,4) M(P,5) M(P,6) M(P,7) M(P,8)
#define DECLQ(P, i) float P##i##x, P##i##y, P##i##z, P##i##w;
#define LOADQ(P, i) { float4 _t = wp[i]; P##i##x = _t.x; P##i##y = _t.y; P##i##z = _t.z; P##i##w = _t.w; }
#define PINQ(P, i)  asm volatile("" : "+v"(P##i##x), "+v"(P##i##y), "+v"(P##i##z), "+v"(P##i##w));
#define FMAQ(P, i)                                                        \
    {  float4 hv = *(const float4*)&hb[(i) * 4];                          \
       z0 = fmaf(P##i##x, hv.x, z0); z1 = fmaf(P##i##y, hv.y, z1);        \
       z2 = fmaf(P##i##z, hv.z, z2); z3 = fmaf(P##i##w, hv.w, z3); }

// array-based dots (fallback kernel only)
#define DOT36(W, H, Z0, Z1, Z2, Z3)                        \
    do {                                                   \
        _Pragma("unroll") for (int _k = 0; _k < 9; ++_k) { \
            float4 hv = *(const float4*)&(H)[_k * 4];      \
            Z0 = fmaf((W)[_k * 4 + 0], hv.x, Z0);          \
            Z1 = fmaf((W)[_k * 4 + 1], hv.y, Z1);          \
            Z2 = fmaf((W)[_k * 4 + 2], hv.z, Z2);          \
            Z3 = fmaf((W)[_k * 4 + 3], hv.w, Z3);          \
        }                                                  \
    } while (0)

#define DOT72(W, H, Z0, Z1, Z2, Z3)                         \
    do {                                                    \
        _Pragma("unroll") for (int _k = 0; _k < 18; ++_k) { \
            float4 hv = *(const float4*)&(H)[_k * 4];       \
            Z0 = fmaf((W)[_k * 4 + 0], hv.x, Z0);           \
            Z1 = fmaf((W)[_k * 4 + 1], hv.y, Z1);           \
            Z2 = fmaf((W)[_k * 4 + 2], hv.z, Z2);           \
            Z3 = fmaf((W)[_k * 4 + 3], hv.w, Z3);           \
        }                                                   \
    } while (0)

// ============ K1: layer-0 REVERSE scan, full batch -> h0r (151 MB ws) ========
// r15 version verbatim (pinned weight quads, 4 chains/block, 512 blocks).
#define SG1 4
#define NTK1 (SG1 * G4)   // 576
__global__ __launch_bounds__(NTK1) void l0rev_kernel(
    const float* __restrict__ x,
    const float* __restrict__ Wih, const float* __restrict__ Whh,
    const float* __restrict__ bih, const float* __restrict__ bhh,
    float* __restrict__ h0r)
{
    const int tid = threadIdx.x;
    const int cc  = tid / G4;
    const int g   = tid % G4;
    const int b   = blockIdx.x * SG1 + cc;

    __shared__ float xs[SG1][TT];
    __shared__ float hs[SG1][40];
    __shared__ float zs[SG1][G4];

    for (int i = g; i < TT; i += G4) xs[cc][i] = x[(size_t)b * TT + i];

    REP9(DECLQ, R)
    {
        const float4* wp = (const float4*)(Whh + g * Hn);
        REP9(LOADQ, R)
    }
    float wx   = Wih[g];
    float bias = bih[g] + bhh[g];
    REP9(PINQ, R)
    asm volatile("" : "+v"(wx), "+v"(bias));

    if (g < 40) hs[cc][g] = 0.0f;
    float c = 0.0f;
    __syncthreads();

    float* dst = h0r + (size_t)b * TT * Hn;

    for (int s = 0; s < TT; ++s) {
        const int t = TT - 1 - s;
        float z0 = fmaf(xs[cc][t], wx, bias), z1 = 0.f, z2 = 0.f, z3 = 0.f;
        {
            const float* hb = hs[cc];
            REP9(FMAQ, R)
        }
        zs[cc][g] = (z0 + z1) + (z2 + z3);
        __syncthreads();
        if (g < Hn) {
            float zi = zs[cc][g], zf = zs[cc][g + 36], zg = zs[cc][g + 72], zo = zs[cc][g + 108];
            c = sigf(zf) * c + sigf(zi) * tanh_fast(zg);
            float h = sigf(zo) * tanh_fast(c);
            hs[cc][g] = h;
            dst[(size_t)t * Hn + g] = h;
        }
        __syncthreads();
    }
}

// ====== K2: skewed fusion, 8 chains/block, transposed LDS weight tables ======
// r16 version verbatim (fastest fused measured: ~1425 us).
#define SG2  8
#define NT2  576
#define NB2  (BB / SG2)   // 256 blocks

__global__ __launch_bounds__(NT2) void fused_fl_kernel(
    const float* __restrict__ x,
    const float* __restrict__ Wih0f, const float* __restrict__ Whh0f,
    const float* __restrict__ bih0f, const float* __restrict__ bhh0f,
    const float* __restrict__ Wih1f, const float* __restrict__ Whh1f,
    const float* __restrict__ bih1f, const float* __restrict__ bhh1f,
    const float* __restrict__ Wih1r,
    const float* __restrict__ bih1r, const float* __restrict__ bhh1r,
    const float* __restrict__ fcW, const float* __restrict__ fcb,
    const float* __restrict__ h0r,
    float* __restrict__ out)
{
    const int tid  = threadIdx.x;
    const int sub  = tid / 288;          // chain half (0: chains 0-3, 1: 4-7)
    const int idx  = tid % 288;
    const int gp   = idx / 72;           // dot group 0..3
    const int rr   = idx % 72;           // row pair: rows rr, rr+72
    const int ch0  = sub * 4;            // first chain of this thread's half
    const int base = blockIdx.x * SG2;
    // combine roles
    const int ca = tid / Hn;             // L0 chain (tid<288)
    const int ia = tid % Hn;             // L0 unit
    const int ct = tid - 288;            // L1 role index
    const int cb = (ct >= 0) ? ct / Hn : 0;
    const int ib = (ct >= 0) ? ct % Hn : 0;

    __shared__ float4 wt0t[9 * G4];      // Whh0f transposed (20.7 KB)
    __shared__ float4 wt1t[18 * G4];     // Wih1f transposed (41.5 KB)
    __shared__ float4 wt3t[9 * G4];      // Whh1f transposed (20.7 KB)
    __shared__ float xs[SG2][TT + 2];
    __shared__ float h0f[2][SG2][40];
    __shared__ float h0rs[2][SG2][40];
    __shared__ float h1s[SG2][40];
    __shared__ float zF[SG2][G4];
    __shared__ float zL[3][SG2][G4];
    __shared__ float red[SG2][Hn];

    // ---------------- one-time staging (transposed: wt[q*144 + row]) --------
    for (int i = tid; i < 9 * G4; i += NT2) {
        int q = i / G4, r = i % G4;
        wt0t[q * G4 + r] = ((const float4*)(Whh0f + r * Hn))[q];
        wt3t[q * G4 + r] = ((const float4*)(Whh1f + r * Hn))[q];
    }
    for (int i = tid; i < 18 * G4; i += NT2) {
        int q = i / G4, r = i % G4;
        wt1t[q * G4 + r] = ((const float4*)(Wih1f + r * 72))[q];
    }
    for (int i = tid; i < SG2 * (TT + 2); i += NT2) {
        int c = i / (TT + 2), t = i % (TT + 2);
        xs[c][t] = (t < TT) ? x[(size_t)(base + c) * TT + t] : 0.0f;
    }
    for (int i = tid; i < 2 * SG2 * 40; i += NT2) {
        (&h0f[0][0][0])[i] = 0.0f;
        (&h0rs[0][0][0])[i] = 0.0f;
    }
    for (int i = tid; i < SG2 * 40; i += NT2) (&h1s[0][0])[i] = 0.0f;

    const int r0 = rr, r1 = rr + 72;
    const float4* wb4 = (gp == 0) ? wt0t
                      : (gp == 1) ? wt1t
                      : (gp == 2) ? (wt1t + 9 * G4)
                                  : wt3t;
    const float wxA = (gp == 0) ? Wih0f[r0] : 0.0f;
    const float wxB = (gp == 0) ? Wih0f[r1] : 0.0f;
    const float bsA = (gp == 0) ? (bih0f[r0] + bhh0f[r0])
                    : (gp == 3) ? (bih1f[r0] + bhh1f[r0]) : 0.0f;
    const float bsB = (gp == 0) ? (bih0f[r1] + bhh0f[r1])
                    : (gp == 3) ? (bih1f[r1] + bhh1f[r1]) : 0.0f;
    float* zt = (gp == 0) ? &zF[0][0] : &zL[gp - 1][0][0];

    const float* srow = h0r + (size_t)(base + cb) * TT * Hn + ib;   // L1-role h0r stream
    float cs0 = 0.0f, cs1 = 0.0f, rvv = 0.0f;
    __syncthreads();

    // ---- prologue: h0f(0) = step(h=0, x0); stage h0r(0); prefetch h0r(1) ----
    if (gp == 0) {
#pragma unroll
        for (int c = 0; c < 4; ++c) {
            zF[ch0 + c][r0] = fmaf(xs[ch0 + c][0], wxA, bsA);
            zF[ch0 + c][r1] = fmaf(xs[ch0 + c][0], wxB, bsB);
        }
    }
    if (ct >= 0) {
        h0rs[0][cb][ib] = srow[0];
        rvv = srow[Hn];
    }
    __syncthreads();
    if (tid < 288) {
        float zi = zF[ca][ia], zg = zF[ca][ia + 72], zo = zF[ca][ia + 108];
        cs0 = sigf(zi) * tanh_fast(zg);       // c=0 start: forget term vanishes
        h0f[0][ca][ia] = sigf(zo) * tanh_fast(cs0);
    }
    __syncthreads();

    int cur = 0;
    for (int t = 0; t < TT; ++t) {
        float rv2 = (ct >= 0 && t + 2 < TT) ? srow[(size_t)(t + 2) * Hn] : 0.0f;

        const float* hb = (gp <= 1) ? &h0f[cur][ch0][0]
                        : (gp == 2) ? &h0rs[cur][ch0][0] : &h1s[ch0][0];
        // branchless init: wxA/B = 0 and bsA/B in {0, b1} for non-gp0 groups
        float x0v = xs[ch0 + 0][t + 1], x1v = xs[ch0 + 1][t + 1];
        float x2v = xs[ch0 + 2][t + 1], x3v = xs[ch0 + 3][t + 1];
        float a00 = fmaf(x0v, wxA, bsA), a01 = fmaf(x1v, wxA, bsA);
        float a02 = fmaf(x2v, wxA, bsA), a03 = fmaf(x3v, wxA, bsA);
        float a10 = fmaf(x0v, wxB, bsB), a11 = fmaf(x1v, wxB, bsB);
        float a12 = fmaf(x2v, wxB, bsB), a13 = fmaf(x3v, wxB, bsB);

#pragma unroll
        for (int i = 0; i < 9; ++i) {
            float4 w0 = wb4[i * G4 + r0];    // stride-1 across lanes: conflict-free
            float4 w1 = wb4[i * G4 + r1];
            float4 h;
            h = *(const float4*)&hb[0 * 40 + i * 4];
            a00 = fmaf(w0.x, h.x, a00); a00 = fmaf(w0.y, h.y, a00);
            a00 = fmaf(w0.z, h.z, a00); a00 = fmaf(w0.w, h.w, a00);
            a10 = fmaf(w1.x, h.x, a10); a10 = fmaf(w1.y, h.y, a10);
            a10 = fmaf(w1.z, h.z, a10); a10 = fmaf(w1.w, h.w, a10);
            h = *(const float4*)&hb[1 * 40 + i * 4];
            a01 = fmaf(w0.x, h.x, a01); a01 = fmaf(w0.y, h.y, a01);
            a01 = fmaf(w0.z, h.z, a01); a01 = fmaf(w0.w, h.w, a01);
            a11 = fmaf(w1.x, h.x, a11); a11 = fmaf(w1.y, h.y, a11);
            a11 = fmaf(w1.z, h.z, a11); a11 = fmaf(w1.w, h.w, a11);
            h = *(const float4*)&hb[2 * 40 + i * 4];
            a02 = fmaf(w0.x, h.x, a02); a02 = fmaf(w0.y, h.y, a02);
            a02 = fmaf(w0.z, h.z, a02); a02 = fmaf(w0.w, h.w, a02);
            a12 = fmaf(w1.x, h.x, a12); a12 = fmaf(w1.y, h.y, a12);
            a12 = fmaf(w1.z, h.z, a12); a12 = fmaf(w1.w, h.w, a12);
            h = *(const float4*)&hb[3 * 40 + i * 4];
            a03 = fmaf(w0.x, h.x, a03); a03 = fmaf(w0.y, h.y, a03);
            a03 = fmaf(w0.z, h.z, a03); a03 = fmaf(w0.w, h.w, a03);
            a13 = fmaf(w1.x, h.x, a13); a13 = fmaf(w1.y, h.y, a13);
            a13 = fmaf(w1.z, h.z, a13); a13 = fmaf(w1.w, h.w, a13);
        }
        zt[(ch0 + 0) * G4 + r0] = a00; zt[(ch0 + 1) * G4 + r0] = a01;
        zt[(ch0 + 2) * G4 + r0] = a02; zt[(ch0 + 3) * G4 + r0] = a03;
        zt[(ch0 + 0) * G4 + r1] = a10; zt[(ch0 + 1) * G4 + r1] = a11;
        zt[(ch0 + 2) * G4 + r1] = a12; zt[(ch0 + 3) * G4 + r1] = a13;
        __syncthreads();

        if (tid < 288) {                       // L0 combine -> h0f(t+1)
            if (t + 1 < TT) {
                float zi = zF[ca][ia],       zf = zF[ca][ia + 36];
                float zg = zF[ca][ia + 72],  zo = zF[ca][ia + 108];
                cs0 = sigf(zf) * cs0 + sigf(zi) * tanh_fast(zg);
                h0f[cur ^ 1][ca][ia] = sigf(zo) * tanh_fast(cs0);
            }
        } else {                               // L1 combine -> h1(t); stage h0r(t+1)
            float zi = zL[0][cb][ib]       + zL[1][cb][ib]       + zL[2][cb][ib];
            float zf = zL[0][cb][ib + 36]  + zL[1][cb][ib + 36]  + zL[2][cb][ib + 36];
            float zg = zL[0][cb][ib + 72]  + zL[1][cb][ib + 72]  + zL[2][cb][ib + 72];
            float zo = zL[0][cb][ib + 108] + zL[1][cb][ib + 108] + zL[2][cb][ib + 108];
            cs1 = sigf(zf) * cs1 + sigf(zi) * tanh_fast(zg);
            h1s[cb][ib] = sigf(zo) * tanh_fast(cs1);
            if (t + 1 < TT) h0rs[cur ^ 1][cb][ib] = rvv;
        }
        __syncthreads();
        rvv = rv2;
        if (t + 1 < TT) cur ^= 1;
    }

    // ---- tail: L1 reverse single step at t=T-1 (h0=c0=0) + FC ----
    {
        const int gpT = tid / G4, gT = tid % G4;
#pragma unroll
        for (int sub2 = 0; sub2 < 2; ++sub2) {
            const int cc = gpT * 2 + sub2;
            float zR = bih1r[gT] + bhh1r[gT];
            const float* wrq = Wih1r + gT * 72;
#pragma unroll
            for (int k = 0; k < Hn; ++k) zR = fmaf(wrq[k],      h0f[cur][cc][k],  zR);
#pragma unroll
            for (int k = 0; k < Hn; ++k) zR = fmaf(wrq[36 + k], h0rs[cur][cc][k], zR);
            zF[cc][gT] = zR;
        }
    }
    __syncthreads();
    if (tid < 288) {
        const int c2 = tid / 36, i2 = tid % 36;
        float zi = zF[c2][i2], zg = zF[c2][i2 + 72], zo = zF[c2][i2 + 108];
        float cR = sigf(zi) * tanh_fast(zg);   // c0=0: forget term vanishes
        float hR = sigf(zo) * tanh_fast(cR);
        red[c2][i2] = fcW[36 + i2] * hR + fcW[i2] * h1s[c2][i2];
    }
    __syncthreads();
    if (tid < SG2) {
        float s2 = fcb[0];
        for (int j = 0; j < Hn; ++j) s2 += red[tid][j];
        out[base + tid] = s2;
    }
}

// ================= FALLBACK PATH (zero workspace, ckpt/recompute) ============
__global__ __launch_bounds__(G4, 1) void fused_all_kernel(
    const float* __restrict__ x,
    const float* __restrict__ Wih0f, const float* __restrict__ Whh0f,
    const float* __restrict__ bih0f, const float* __restrict__ bhh0f,
    const float* __restrict__ Wih0r, const float* __restrict__ Whh0r,
    const float* __restrict__ bih0r, const float* __restrict__ bhh0r,
    const float* __restrict__ Wih1f, const float* __restrict__ Whh1f,
    const float* __restrict__ bih1f, const float* __restrict__ bhh1f,
    const float* __restrict__ Wih1r,
    const float* __restrict__ bih1r, const float* __restrict__ bhh1r,
    const float* __restrict__ fcW, const float* __restrict__ fcb,
    float* __restrict__ out)
{
    const int g = threadIdx.x;
    const int b = blockIdx.x;

    __shared__ float xs[TT];
    __shared__ float cbuf[64][Hn];
    __shared__ float ckpt_h[8][Hn], ckpt_c[8][Hn];
    __shared__ float hr[40], h0s[80], hs1[40], zs[G4], red[40];

    for (int i = g; i < TT; i += G4) xs[i] = x[(size_t)b * TT + i];

    float wr[Hn], wf[Hn];
#pragma unroll
    for (int k = 0; k < Hn; ++k) wr[k] = Whh0r[g * Hn + k];
#pragma unroll
    for (int k = 0; k < Hn; ++k) wf[k] = Whh0f[g * Hn + k];
    const float wxr = Wih0r[g], br = bih0r[g] + bhh0r[g];
    const float wxf = Wih0f[g], bf = bih0f[g] + bhh0f[g];
    float w1i[72];
#pragma unroll
    for (int k = 0; k < 72; ++k) w1i[k] = Wih1f[g * 72 + k];
    float w1h[Hn];
#pragma unroll
    for (int k = 0; k < Hn; ++k) w1h[k] = Whh1f[g * Hn + k];
    const float b1 = bih1f[g] + bhh1f[g];

    if (g < Hn) hr[g] = 0.0f;
    float cr = 0.0f;
    __syncthreads();
    for (int s = 0; s < TT; ++s) {
        const int t = TT - 1 - s;
        if ((t & 63) == 63 && g < Hn) { ckpt_h[t >> 6][g] = hr[g]; ckpt_c[t >> 6][g] = cr; }
        float z0 = fmaf(xs[t], wxr, br), z1 = 0.f, z2 = 0.f, z3 = 0.f;
        DOT36(wr, hr, z0, z1, z2, z3);
        zs[g] = (z0 + z1) + (z2 + z3);
        __syncthreads();
        if (g < Hn) {
            float zi = zs[g], zf = zs[g + 36], zg = zs[g + 72], zo = zs[g + 108];
            cr = sigf(zf) * cr + sigf(zi) * tanh_fast(zg);
            hr[g] = sigf(zo) * tanh_fast(cr);
        }
        __syncthreads();
    }

    if (g < Hn) { h0s[g] = 0.0f; hs1[g] = 0.0f; }
    float c0 = 0.0f, c1 = 0.0f;
    __syncthreads();

    for (int m = 0; m < 8; ++m) {
        if (g < Hn) { hr[g] = ckpt_h[m][g]; cr = ckpt_c[m][g]; }
        __syncthreads();
        for (int j = 0; j < 64; ++j) {
            const int t = m * 64 + 63 - j;
            float z0 = fmaf(xs[t], wxr, br), z1 = 0.f, z2 = 0.f, z3 = 0.f;
            DOT36(wr, hr, z0, z1, z2, z3);
            zs[g] = (z0 + z1) + (z2 + z3);
            __syncthreads();
            if (g < Hn) {
                float zi = zs[g], zf = zs[g + 36], zg = zs[g + 72], zo = zs[g + 108];
                cr = sigf(zf) * cr + sigf(zi) * tanh_fast(zg);
                float h = sigf(zo) * tanh_fast(cr);
                hr[g] = h;
                cbuf[t & 63][g] = h;
            }
            __syncthreads();
        }
        for (int j = 0; j < 64; ++j) {
            const int t = m * 64 + j;
            float z0 = fmaf(xs[t], wxf, bf), z1 = 0.f, z2 = 0.f, z3 = 0.f;
            DOT36(wf, h0s, z0, z1, z2, z3);
            zs[g] = (z0 + z1) + (z2 + z3);
            __syncthreads();
            if (g < Hn) {
                float zi = zs[g], zf = zs[g + 36], zg = zs[g + 72], zo = zs[g + 108];
                c0 = sigf(zf) * c0 + sigf(zi) * tanh_fast(zg);
                h0s[g] = sigf(zo) * tanh_fast(c0);
            } else if (g < 72) {
                h0s[g] = cbuf[j][g - 36];
            }
            __syncthreads();
            float y0 = b1, y1 = 0.f, y2 = 0.f, y3 = 0.f;
            DOT72(w1i, h0s, y0, y1, y2, y3);
            DOT36(w1h, hs1, y0, y1, y2, y3);
            zs[g] = (y0 + y1) + (y2 + y3);
            __syncthreads();
            if (g < Hn) {
                float zi = zs[g], zf = zs[g + 36], zg = zs[g + 72], zo = zs[g + 108];
                c1 = sigf(zf) * c1 + sigf(zi) * tanh_fast(zg);
                hs1[g] = sigf(zo) * tanh_fast(c1);
            }
            __syncthreads();
        }
    }

    float zR = bih1r[g] + bhh1r[g];
#pragma unroll
    for (int k = 0; k < 72; ++k) zR = fmaf(Wih1r[g * 72 + k], h0s[k], zR);
    zs[g] = zR;
    __syncthreads();
    if (g < Hn) {
        float zi = zs[g], zg = zs[g + 72], zo = zs[g + 108];
        float c  = sigf(zi) * tanh_fast(zg);
        float hrv = sigf(zo) * tanh_fast(c);
        red[g] = fcW[36 + g] * hrv + fcW[g] * hs1[g];
    }
    __syncthreads();
    if (g == 0) {
        float s = fcb[0];
        for (int j = 0; j < Hn; ++j) s += red[j];
        out[b] = s;
    }
}

extern "C" void kernel_launch(void* const* d_in, const int* in_sizes, int n_in,
                              void* d_out, int out_size, void* d_ws, size_t ws_size,
                              hipStream_t stream)
{
    const float* x     = (const float*)d_in[0];
    const float* Wih0f = (const float*)d_in[1];
    const float* Whh0f = (const float*)d_in[2];
    const float* bih0f = (const float*)d_in[3];
    const float* bhh0f = (const float*)d_in[4];
    const float* Wih0r = (const float*)d_in[5];
    const float* Whh0r = (const float*)d_in[6];
    const float* bih0r = (const float*)d_in[7];
    const float* bhh0r = (const float*)d_in[8];
    const float* Wih1f = (const float*)d_in[9];
    const float* Whh1f = (const float*)d_in[10];
    const float* bih1f = (const float*)d_in[11];
    const float* bhh1f = (const float*)d_in[12];
    const float* Wih1r = (const float*)d_in[13];
    const float* bih1r = (const float*)d_in[15];
    const float* bhh1r = (const float*)d_in[16];
    const float* fcW   = (const float*)d_in[17];
    const float* fcb   = (const float*)d_in[18];

    const size_t need = (size_t)BB * TT * Hn * sizeof(float);   // 151 MB (known-safe)
    if (d_ws != nullptr && ws_size >= need) {
        float* h0r = (float*)d_ws;
        l0rev_kernel<<<BB / SG1, NTK1, 0, stream>>>(x, Wih0r, Whh0r, bih0r, bhh0r, h0r);
        fused_fl_kernel<<<NB2, NT2, 0, stream>>>(
            x, Wih0f, Whh0f, bih0f, bhh0f, Wih1f, Whh1f, bih1f, bhh1f,
            Wih1r, bih1r, bhh1r, fcW, fcb, h0r, (float*)d_out);
    } else {
        fused_all_kernel<<<BB, G4, 0, stream>>>(
            x, Wih0f, Whh0f, bih0f, bhh0f, Wih0r, Whh0r, bih0r, bhh0r,
            Wih1f, Whh1f, bih1f, bhh1f, Wih1r, bih1r, bhh1r, fcW, fcb,
            (float*)d_out);
    }
}